// Round 7
// baseline (418.653 us; speedup 1.0000x reference)
//
#include <hip/hip_runtime.h>

#define D 128            // D_IN == D_OUT == 128
#define NEG_SLOPE 0.01f
#define NBK 256          // radix buckets (dst>>9), covers N <= 131072
#define BK2 9            // 512 dsts per bucket
#define TILE 4096        // edges per partition block
#define STR 136          // LDS W stride in bf16 elems (pad 8 -> 2-way alias, free)

typedef __attribute__((ext_vector_type(8))) short short8;
typedef __attribute__((ext_vector_type(4))) float floatx4;

// bf16 helpers
__device__ __forceinline__ unsigned f2bf_rne(float x) {
    unsigned u = __float_as_uint(x);
    return (u + 0x7fffu + ((u >> 16) & 1u)) >> 16;
}
#define BF_LO(u) __uint_as_float((u) << 16)
#define BF_HI(u) __uint_as_float((u) & 0xffff0000u)

// ---- z = h @ W via SPLIT-bf16 MFMA (fp32-accurate: hi*hi + lo*hi + hi*lo).
// Wave = 16 rows x 128 cols, 8 C-frags; W staged once/block in LDS
// transposed+split; scores fused from C-frags.
__global__ __launch_bounds__(256) void gemm_zs(const float* __restrict__ h,
                                               const float* __restrict__ W,
                                               const float* __restrict__ aw,
                                               unsigned short* __restrict__ z,
                                               float* __restrict__ s_src,
                                               float* __restrict__ s_dst, int N) {
    __shared__ unsigned short ws_hi[D * STR];   // 34 KB
    __shared__ unsigned short ws_lo[D * STR];   // 34 KB
    const int t = threadIdx.x;
    for (int i = t; i < D * D; i += 256) {
        int k = i >> 7, n = i & 127;
        float x = W[i];
        unsigned hi = f2bf_rne(x);
        float hf = __uint_as_float(hi << 16);
        unsigned lo = __float_as_uint(x - hf) >> 16;
        ws_hi[n * STR + k] = (unsigned short)hi;
        ws_lo[n * STR + k] = (unsigned short)lo;
    }
    __syncthreads();

    const int lane = t & 63, quad = lane >> 4, l16 = lane & 15;
    const int rowbase = blockIdx.x * 64 + (t >> 6) * 16;
    const int arow = min(rowbase + l16, N - 1);
    const float* __restrict__ hrow = h + (size_t)arow * D;

    floatx4 acc[8];
#pragma unroll
    for (int ct = 0; ct < 8; ++ct) acc[ct] = (floatx4){0.f, 0.f, 0.f, 0.f};

#pragma unroll
    for (int kk = 0; kk < 4; ++kk) {
        const int k0 = kk * 32 + quad * 8;
        float4 x0 = *(const float4*)&hrow[k0];
        float4 x1 = *(const float4*)&hrow[k0 + 4];
        float xs[8] = {x0.x, x0.y, x0.z, x0.w, x1.x, x1.y, x1.z, x1.w};
        union { short8 v; unsigned short u[8]; } ahi, alo;
#pragma unroll
        for (int i = 0; i < 8; ++i) {
            unsigned hi = f2bf_rne(xs[i]);
            float hf = __uint_as_float(hi << 16);
            ahi.u[i] = (unsigned short)hi;
            alo.u[i] = (unsigned short)(__float_as_uint(xs[i] - hf) >> 16);
        }
#pragma unroll
        for (int ct = 0; ct < 8; ++ct) {
            const int bo = (ct * 16 + l16) * STR + k0;
            short8 bhi = *(const short8*)&ws_hi[bo];
            short8 blo = *(const short8*)&ws_lo[bo];
            acc[ct] = __builtin_amdgcn_mfma_f32_16x16x32_bf16(ahi.v, bhi, acc[ct], 0, 0, 0);
            acc[ct] = __builtin_amdgcn_mfma_f32_16x16x32_bf16(alo.v, bhi, acc[ct], 0, 0, 0);
            acc[ct] = __builtin_amdgcn_mfma_f32_16x16x32_bf16(ahi.v, blo, acc[ct], 0, 0, 0);
        }
    }

#pragma unroll
    for (int ct = 0; ct < 8; ++ct)
#pragma unroll
        for (int reg = 0; reg < 4; ++reg) {
            int r = rowbase + quad * 4 + reg;
            if (r < N)
                z[(size_t)r * D + ct * 16 + l16] = (unsigned short)f2bf_rne(acc[ct][reg]);
        }

    float ps[4] = {0.f, 0.f, 0.f, 0.f}, pd[4] = {0.f, 0.f, 0.f, 0.f};
#pragma unroll
    for (int ct = 0; ct < 8; ++ct) {
        float as = aw[ct * 16 + l16];
        float ad = aw[128 + ct * 16 + l16];
#pragma unroll
        for (int reg = 0; reg < 4; ++reg) {
            ps[reg] = fmaf(acc[ct][reg], as, ps[reg]);
            pd[reg] = fmaf(acc[ct][reg], ad, pd[reg]);
        }
    }
#pragma unroll
    for (int reg = 0; reg < 4; ++reg)
#pragma unroll
        for (int o = 1; o < 16; o <<= 1) {
            ps[reg] += __shfl_xor(ps[reg], o, 64);
            pd[reg] += __shfl_xor(pd[reg], o, 64);
        }
    if (l16 == 0) {
#pragma unroll
        for (int reg = 0; reg < 4; ++reg) {
            int r = rowbase + quad * 4 + reg;
            if (r < N) { s_src[r] = ps[reg]; s_dst[r] = pd[reg]; }
        }
    }
}

// ---------------- radix partition: LDS histograms, coalesced writes ----------
__global__ __launch_bounds__(256) void r_count(const int* __restrict__ edst,
                                               int* __restrict__ cnts, int E, int nblk) {
    __shared__ int hist[NBK];
    const int t = threadIdx.x, blk = blockIdx.x;
    hist[t] = 0;
    __syncthreads();
    const int e0 = blk * TILE, e1 = min(e0 + TILE, E);
    for (int e = e0 + t; e < e1; e += 256)
        atomicAdd(&hist[edst[e] >> BK2], 1);
    __syncthreads();
    cnts[t * nblk + blk] = hist[t];     // bucket-major count matrix
}

// single block: exclusive scan of cnts (linear = bucket-major) -> dense bases
__global__ __launch_bounds__(1024) void r_scan(int* __restrict__ cnts,
                                               int* __restrict__ bstart,
                                               int* __restrict__ offs,
                                               int M, int nblk, int E, int N) {
    __shared__ int part[1024];
    const int t = threadIdx.x;
    const int chunk = (M + 1023) >> 10;
    const int i0 = t * chunk, i1 = min(i0 + chunk, M);
    int s = 0;
    for (int i = i0; i < i1; ++i) s += cnts[i];
    part[t] = s;
    __syncthreads();
    for (int off = 1; off < 1024; off <<= 1) {
        int v = (t >= off) ? part[t - off] : 0;
        __syncthreads();
        part[t] += v;
        __syncthreads();
    }
    int run = part[t] - s;
    for (int i = i0; i < i1; ++i) { int c = cnts[i]; cnts[i] = run; run += c; }
    __syncthreads();
    for (int b = t; b < NBK; b += 1024) bstart[b] = cnts[b * nblk];
    if (t == 0) { bstart[NBK] = E; offs[N] = E; }
}

// re-read tile; LDS cursors seeded from scanned bases -> each block's edges
// for one bucket land CONTIGUOUSLY (~16-edge / 64B runs, write-amp ~1x).
__global__ __launch_bounds__(256) void r_scatter(const int* __restrict__ esrc,
                                                 const int* __restrict__ edst,
                                                 const int* __restrict__ cnts,
                                                 int* __restrict__ pairs, int E, int nblk) {
    __shared__ int cur[NBK];
    const int t = threadIdx.x, blk = blockIdx.x;
    cur[t] = cnts[t * nblk + blk];
    __syncthreads();
    const int e0 = blk * TILE, e1 = min(e0 + TILE, E);
    for (int e = e0 + t; e < e1; e += 256) {
        int d = edst[e];
        int pos = atomicAdd(&cur[d >> BK2], 1);
        pairs[pos] = (esrc[e] << BK2) | (d & 511);   // src<2^17, 17+9=26 bits
    }
}

// one block per 512-dst bucket: LDS histogram + scan -> offs + adj (dense).
__global__ __launch_bounds__(256) void fine_build(const int* __restrict__ pairs,
                                                  const int* __restrict__ bstart,
                                                  int* __restrict__ offs,
                                                  int* __restrict__ adj, int N) {
    __shared__ int cnt[512], exc[512], cur[512], part[256];
    const int b = blockIdx.x, base = b << BK2, t = threadIdx.x;
    const int nd = min(512, N - base);
    cnt[t] = 0; cnt[t + 256] = 0; cur[t] = 0; cur[t + 256] = 0;
    __syncthreads();
    const int s0 = bstart[b], e0v = bstart[b + 1];
    for (int i = s0 + t; i < e0v; i += 256)
        atomicAdd(&cnt[pairs[i] & 511], 1);
    __syncthreads();
    // 512-wide exclusive scan via 256 pair-partials
    int c0 = cnt[2 * t], c1 = cnt[2 * t + 1], psum = c0 + c1;
    part[t] = psum;
    __syncthreads();
    for (int off = 1; off < 256; off <<= 1) {
        int v = (t >= off) ? part[t - off] : 0;
        __syncthreads();
        part[t] += v;
        __syncthreads();
    }
    int ex = part[t] - psum;
    exc[2 * t] = ex; exc[2 * t + 1] = ex + c0;
    __syncthreads();
    for (int dd = t; dd < nd; dd += 256) offs[base + dd] = s0 + exc[dd];
    for (int i = s0 + t; i < e0v; i += 256) {
        int pk = pairs[i];
        int dd = pk & 511;
        int pos = s0 + exc[dd] + atomicAdd(&cur[dd], 1);
        adj[pos] = pk >> BK2;
    }
}

// ---------------- per-dst-node softmax + weighted sum: one wave per node ------
// z rows bf16 (256B): each 16-lane QUAD covers one row (16B/lane uint4),
// 4 edges/iter x2 unroll. Every __shfl executes with ALL 64 lanes active;
// validity via value predication of the shfl'd weight.
__global__ __launch_bounds__(256) void aggregate(const unsigned short* __restrict__ z,
                                                 const float* __restrict__ s_src,
                                                 const float* __restrict__ s_dst,
                                                 const int* __restrict__ offs,
                                                 const int* __restrict__ adj,
                                                 float* __restrict__ out, int N) {
    const int lane = threadIdx.x & 63;
    const int q    = lane >> 4;
    const int l16  = lane & 15;
    const int node = blockIdx.x * 4 + (threadIdx.x >> 6);
    if (node >= N) return;
    const int beg = offs[node];
    const int cnt = offs[node + 1] - beg;
    const float sd = s_dst[node];

    float a[8] = {0.f,0.f,0.f,0.f,0.f,0.f,0.f,0.f};
    float bacc[8] = {0.f,0.f,0.f,0.f,0.f,0.f,0.f,0.f};

    auto fma8 = [&](float* ac, float w, const uint4& v) {
        ac[0] = fmaf(w, BF_LO(v.x), ac[0]); ac[1] = fmaf(w, BF_HI(v.x), ac[1]);
        ac[2] = fmaf(w, BF_LO(v.y), ac[2]); ac[3] = fmaf(w, BF_HI(v.y), ac[3]);
        ac[4] = fmaf(w, BF_LO(v.z), ac[4]); ac[5] = fmaf(w, BF_HI(v.z), ac[5]);
        ac[6] = fmaf(w, BF_LO(v.w), ac[6]); ac[7] = fmaf(w, BF_HI(v.w), ac[7]);
    };

    if (cnt <= 64) {
        int s = 0; float e = -INFINITY;
        if (lane < cnt) {
            s = adj[beg + lane];
            float t = s_src[s] + sd;
            e = (t >= 0.f) ? t : NEG_SLOPE * t;
        }
        float mx = e;
#pragma unroll
        for (int o = 32; o; o >>= 1) mx = fmaxf(mx, __shfl_xor(mx, o, 64));
        float ex = (lane < cnt) ? __expf(e - mx) : 0.f;
        float sum = ex;
#pragma unroll
        for (int o = 32; o; o >>= 1) sum += __shfl_xor(sum, o, 64);
        const float inv = (cnt > 0) ? 1.f / sum : 0.f;
        const float w = ex * inv;

        for (int jj = 0; jj < cnt; jj += 8) {
            const int ja = jj + q;
            const int jb = ja + 4;
            float wa = __shfl(w, ja, 64); int sa = __shfl(s, ja, 64);
            float wb = __shfl(w, jb, 64); int sb = __shfl(s, jb, 64);
            wa = (ja < cnt) ? wa : 0.f;
            wb = (jb < cnt) ? wb : 0.f;
            uint4 za = *(const uint4*)&z[(size_t)sa * D + l16 * 8];
            uint4 zb = *(const uint4*)&z[(size_t)sb * D + l16 * 8];
            fma8(a, wa, za);
            fma8(bacc, wb, zb);
        }
    } else {
        float mx = -INFINITY;
        for (int j = lane; j < cnt; j += 64) {
            float t = s_src[adj[beg + j]] + sd;
            t = (t >= 0.f) ? t : NEG_SLOPE * t;
            mx = fmaxf(mx, t);
        }
#pragma unroll
        for (int o = 32; o; o >>= 1) mx = fmaxf(mx, __shfl_xor(mx, o, 64));
        float sum = 0.f;
        for (int j = lane; j < cnt; j += 64) {
            float t = s_src[adj[beg + j]] + sd;
            t = (t >= 0.f) ? t : NEG_SLOPE * t;
            sum += __expf(t - mx);
        }
#pragma unroll
        for (int o = 32; o; o >>= 1) sum += __shfl_xor(sum, o, 64);
        const float inv = 1.f / sum;
        for (int base2 = 0; base2 < cnt; base2 += 64) {
            const int cc = min(64, cnt - base2);
            int s = 0; float w = 0.f;
            if (lane < cc) {
                s = adj[beg + base2 + lane];
                float t = s_src[s] + sd;
                t = (t >= 0.f) ? t : NEG_SLOPE * t;
                w = __expf(t - mx) * inv;
            }
            for (int jj = 0; jj < cc; jj += 8) {
                const int ja = jj + q;
                const int jb = ja + 4;
                float wa = __shfl(w, ja, 64); int sa = __shfl(s, ja, 64);
                float wb = __shfl(w, jb, 64); int sb = __shfl(s, jb, 64);
                wa = (ja < cc) ? wa : 0.f;
                wb = (jb < cc) ? wb : 0.f;
                uint4 za = *(const uint4*)&z[(size_t)sa * D + l16 * 8];
                uint4 zb = *(const uint4*)&z[(size_t)sb * D + l16 * 8];
                fma8(a, wa, za);
                fma8(bacc, wb, zb);
            }
        }
    }

#pragma unroll
    for (int i = 0; i < 8; ++i) {
        a[i] += bacc[i];
        a[i] += __shfl_xor(a[i], 16, 64);
        a[i] += __shfl_xor(a[i], 32, 64);
    }
    if (q == 0) {
        float* o = &out[(size_t)node * D + l16 * 8];
        *(float4*)o       = make_float4(a[0], a[1], a[2], a[3]);
        *(float4*)(o + 4) = make_float4(a[4], a[5], a[6], a[7]);
    }
}

// ---------------- launch ----------------
extern "C" void kernel_launch(void* const* d_in, const int* in_sizes, int n_in,
                              void* d_out, int out_size, void* d_ws, size_t ws_size,
                              hipStream_t stream) {
    const float* h    = (const float*)d_in[0];
    const float* W    = (const float*)d_in[1];
    const float* aw   = (const float*)d_in[2];
    const int*   esrc = (const int*)d_in[3];
    const int*   edst = (const int*)d_in[4];
    float* out = (float*)d_out;

    const int N = in_sizes[0] / D;     // 100000
    const int E = in_sizes[3];         // 1600000
    const int NBLK = (E + TILE - 1) / TILE;      // 391
    const int M = NBK * NBLK;
    const int NF = (N + 511) >> BK2;             // 196 fine buckets

    char* p = (char*)d_ws;
    auto carve = [&](size_t bytes) {
        void* r = (void*)p;
        p += (bytes + 255) & ~size_t(255);
        return r;
    };
    unsigned short* z = (unsigned short*)carve(size_t(N) * D * sizeof(unsigned short));
    float* s_src  = (float*)carve(size_t(N) * sizeof(float));
    float* s_dst  = (float*)carve(size_t(N) * sizeof(float));
    int*   offs   = (int*)carve(size_t(N + 1) * sizeof(int));
    int*   adj    = (int*)carve(size_t(E) * sizeof(int));
    int*   pairs  = (int*)carve(size_t(E) * sizeof(int));
    int*   cnts   = (int*)carve(size_t(M) * sizeof(int));
    int*   bstart = (int*)carve(size_t(NBK + 1) * sizeof(int));
    (void)ws_size; (void)n_in; (void)out_size;

    gemm_zs<<<(N + 63) / 64, 256, 0, stream>>>(h, W, aw, z, s_src, s_dst, N);
    r_count<<<NBLK, 256, 0, stream>>>(edst, cnts, E, NBLK);
    r_scan<<<1, 1024, 0, stream>>>(cnts, bstart, offs, M, NBLK, E, N);
    r_scatter<<<NBLK, 256, 0, stream>>>(esrc, edst, cnts, pairs, E, NBLK);
    fine_build<<<NF, 256, 0, stream>>>(pairs, bstart, offs, adj, N);
    aggregate<<<(N + 3) / 4, 256, 0, stream>>>(z, s_src, s_dst, offs, adj, out, N);
}